// Round 17
// baseline (421.044 us; speedup 1.0000x reference)
//
#include <hip/hip_runtime.h>
#include <hip/hip_bf16.h>

// Sparse graph-attention Gumbel mask.
//
// With M = Wq^T Wk [E,E]:
//   w_ui[e] = adj*( Xu[r]·C[c] + t1[r] + u1[c] + c0 ),  C = Xi M^T
//   w_iu[e] = adj*( Xu[r]·D[c] + t2[r] + u2[c] + c0 ),  D = Xi M
//
// R17 = R16 (fixed-capacity c-binning, bin-per-16-lane-group edge kernel,
// no-max f64 softmax via fast exp, lane0/1 tail split, f32 final pass)
// + NONTEMPORAL stores for all scattered small writes (L12 in edge/ovf,
//   SA/SB in scatter): avoids L2 write-allocate RMW line fetches
//   (~100MB in edge FETCH, ~100MB in scatter) for 8-20B writes.
// + fin4 2-wide (float4 L12 / int2 rows+cols loads).

#define EMB 128
#define TAUINV 2.0f
#define LOG2E 1.44269504f
#define CAP 128
#define OCAP 65536

typedef float fx2 __attribute__((ext_vector_type(2)));
typedef int ix4 __attribute__((ext_vector_type(4)));

__device__ __forceinline__ unsigned fkey(float f) {
    unsigned u = __float_as_uint(f);
    return (u & 0x80000000u) ? ~u : (u | 0x80000000u);
}
__device__ __forceinline__ float fdecode(unsigned u) {
    return __uint_as_float((u & 0x80000000u) ? (u ^ 0x80000000u) : ~u);
}

// exp(lg) as double without overflow: exp2f fraction + ldexp integer part.
__device__ __forceinline__ double dexp_fast(float lg) {
    float t = lg * LOG2E;
    float kf = floorf(t);
    float f = exp2f(t - kf);
    return ldexp((double)f, (int)kf);
}

// ---- BIGM[k][j] (j<128: M[j][k]; j>=128: M[k][j-128]), v1, v2, c0, flag
__global__ void k_prep(const float* __restrict__ Wq, const float* __restrict__ Wk,
                       const float* __restrict__ bq, const float* __restrict__ bk,
                       float* __restrict__ BIGM, float* __restrict__ v1,
                       float* __restrict__ v2, float* __restrict__ c0) {
    int e1 = blockIdx.x, e2 = threadIdx.x;
    float acc = 0.f;
    for (int a = 0; a < EMB; ++a) acc += Wq[a * EMB + e1] * Wk[a * EMB + e2];
    BIGM[e2 * 256 + e1] = acc;
    BIGM[e1 * 256 + 128 + e2] = acc;
    if (e2 == 0) { float s = 0.f; for (int a = 0; a < EMB; ++a) s += Wq[a * EMB + e1] * bk[a]; v1[e1] = s; }
    if (e2 == 1) { float s = 0.f; for (int a = 0; a < EMB; ++a) s += Wk[a * EMB + e1] * bq[a]; v2[e1] = s; }
    if (e1 == 0 && e2 == 2) { float s = 0.f; for (int a = 0; a < EMB; ++a) s += bq[a] * bk[a]; c0[0] = s; }
    if (e1 == 0 && e2 == 3) { float s = 0.f; for (int a = 0; a < EMB; ++a) s += fabsf(bq[a]) + fabsf(bk[a]); c0[1] = s; }
}

// ---- CD[m][j] = sum_k Xi[m][k] * BIGM[k][j]
__global__ __launch_bounds__(256) void k_cd(const float* __restrict__ Xi,
                                            const float* __restrict__ BIGM,
                                            float* __restrict__ CD, int nItems) {
    __shared__ float Xs[32][EMB];
    __shared__ float Ms[32][256];
    const int t = threadIdx.x;
    const int m0 = blockIdx.x * 32;

    const float4* Xi4 = (const float4*)Xi;
    float4* Xs4 = (float4*)Xs;
    for (int idx = t; idx < 32 * 32; idx += 256) {
        int r = idx >> 5, c = idx & 31;
        int row = m0 + r;
        Xs4[idx] = (row < nItems) ? Xi4[(size_t)row * 32 + c]
                                  : make_float4(0.f, 0.f, 0.f, 0.f);
    }

    const int tc = t & 63;
    const int tr = t >> 6;
    float4 acc[8] = {};

    const float4* BG4 = (const float4*)BIGM;
    float4* Ms4 = (float4*)Ms;
    for (int kc = 0; kc < EMB; kc += 32) {
        __syncthreads();
        for (int idx = t; idx < 32 * 64; idx += 256)
            Ms4[idx] = BG4[(size_t)(kc + (idx >> 6)) * 64 + (idx & 63)];
        __syncthreads();
#pragma unroll
        for (int kk = 0; kk < 32; ++kk) {
            float4 w = Ms4[kk * 64 + tc];
#pragma unroll
            for (int i = 0; i < 8; ++i) {
                float x = Xs[tr * 8 + i][kc + kk];
                acc[i].x += x * w.x; acc[i].y += x * w.y;
                acc[i].z += x * w.z; acc[i].w += x * w.w;
            }
        }
    }
#pragma unroll
    for (int i = 0; i < 8; ++i) {
        int row = m0 + tr * 8 + i;
        if (row < nItems)
            ((float4*)(CD + (size_t)row * 256))[tc] = acc[i];
    }
}

// ---- fused rowdots, packed: t12[r]={Xu.v1,Xu.v2}, u12[c]={Xi.v2,Xi.v1}
__global__ void k_rowdot2(const float* __restrict__ Xu, const float* __restrict__ Xi,
                          int U, int I,
                          const float* __restrict__ v1, const float* __restrict__ v2,
                          float2* __restrict__ t12, float2* __restrict__ u12) {
    int g = blockIdx.x * 8 + (threadIdx.x >> 5);
    int l = threadIdx.x & 31;
    if (g >= U + I) return;
    const float* X = (g < U) ? (Xu + (size_t)g * EMB) : (Xi + (size_t)(g - U) * EMB);
    float4 x = ((const float4*)X)[l];
    float4 av = ((const float4*)v1)[l];
    float4 bv = ((const float4*)v2)[l];
    float pa = x.x * av.x + x.y * av.y + x.z * av.z + x.w * av.w;
    float pb = x.x * bv.x + x.y * bv.y + x.z * bv.z + x.w * bv.w;
    for (int off = 16; off; off >>= 1) { pa += __shfl_xor(pa, off); pb += __shfl_xor(pb, off); }
    if (l == 0) {
        if (g < U) t12[g] = make_float2(pa, pb);
        else       u12[g - U] = make_float2(pb, pa);
    }
}

// ---- fixed-cap scatter: pos=atomicAdd(cnt[c]); SA[c*CAP+pos]={r,eidx,a',b1},
// SB=b2, both via nontemporal stores (no write-allocate RMW).
__global__ void k_scatter_fc(const int* __restrict__ rows, const int* __restrict__ cols,
                             const float* __restrict__ adj, const float* __restrict__ gu1,
                             const float* __restrict__ gu2,
                             const float2* __restrict__ t12, const float2* __restrict__ u12,
                             const float* __restrict__ c0p, int nnz,
                             unsigned* __restrict__ cnt, ix4* __restrict__ SA,
                             float* __restrict__ SB, int* __restrict__ OV,
                             unsigned* __restrict__ ovfc) {
    const float c0 = c0p[0];
    const bool useb = (c0p[1] != 0.f);
    int i = blockIdx.x * blockDim.x + threadIdx.x, st = gridDim.x * blockDim.x;
    for (int e = i; e < nnz; e += st) {
        int r = rows[e], c = cols[e];
        unsigned pos = atomicAdd(&cnt[c], 1u);
        float a = adj[e];
        float g1 = logf(-logf(gu1[e]));   // logf: u near 1 needs relative accuracy
        float g2 = logf(-logf(gu2[e]));
        float b1 = -g1 * TAUINV;
        float b2 = -g2 * TAUINV;
        if (useb) {
            float2 tt = t12[r];
            float2 uu = u12[c];
            b1 += a * (tt.x + uu.x + c0) * TAUINV;
            b2 += a * (tt.y + uu.y + c0) * TAUINV;
        }
        if (pos < CAP) {
            size_t s = (size_t)c * CAP + pos;
            ix4 v; v.x = r; v.y = e; v.z = __float_as_int(a * TAUINV); v.w = __float_as_int(b1);
            __builtin_nontemporal_store(v, SA + s);
            __builtin_nontemporal_store(b2, SB + s);
        } else {
            unsigned o = atomicAdd(ovfc, 1u);
            if (o < OCAP) {
                int* p = OV + (size_t)o * 6;
                p[0] = r; p[1] = c; p[2] = e;
                p[3] = __float_as_int(a * TAUINV);
                p[4] = __float_as_int(b1); p[5] = __float_as_int(b2);
            }
        }
    }
}

// ---- edge kernel: one bin per 16-lane group; CD register-held; lane0/1
// tail split with fast exp; s2 plain store; L12 via nontemporal store.
__global__ __launch_bounds__(256) void k_edge14(
    const float* __restrict__ Xu, const float* __restrict__ CD,
    const unsigned* __restrict__ cnt, const ix4* __restrict__ SA,
    const float* __restrict__ SB,
    float* __restrict__ L12, double* __restrict__ s1d, double* __restrict__ s2d,
    int I) {
    const int g = threadIdx.x >> 4, l = threadIdx.x & 15;
    const int c = blockIdx.x * 16 + g;
    if (c >= I) return;
    unsigned n = cnt[c]; if (n > CAP) n = CAP;
    if (n == 0) return;
    const unsigned lo = (unsigned)c * CAP;
    const unsigned hi = lo + n;
    const float4* cd = (const float4*)(CD + (size_t)c * 256);
    const float4 cv0 = cd[l], cv1 = cd[l + 16];
    const float4 dv0 = cd[l + 32], dv1 = cd[l + 48];
    double s2acc = 0.0;
    for (unsigned j = lo; j < hi; ++j) {
        ix4 m = SA[j];
        float b2s = SB[j];
        const float4* xu = (const float4*)(Xu + (size_t)m.x * EMB);
        float4 x0 = xu[l], x1 = xu[l + 16];
        float p1 = x0.x * cv0.x + x0.y * cv0.y + x0.z * cv0.z + x0.w * cv0.w
                 + x1.x * cv1.x + x1.y * cv1.y + x1.z * cv1.z + x1.w * cv1.w;
        float p2 = x0.x * dv0.x + x0.y * dv0.y + x0.z * dv0.z + x0.w * dv0.w
                 + x1.x * dv1.x + x1.y * dv1.y + x1.z * dv1.z + x1.w * dv1.w;
#pragma unroll
        for (int off = 1; off < 16; off <<= 1) {
            p1 += __shfl_xor(p1, off);
            p2 += __shfl_xor(p2, off);
        }
        if (l < 2) {
            float aP = __int_as_float(m.z);
            float bP = (l == 0) ? __int_as_float(m.w) : b2s;
            float lg = fmaf(aP, (l == 0) ? p1 : p2, bP);
            double ev = dexp_fast(lg);
            __builtin_nontemporal_store(lg, L12 + (size_t)m.y * 2 + l);
            if (l == 0) unsafeAtomicAdd(s1d + m.x, ev);
            else        s2acc += ev;
        }
    }
    if (l == 1) s2d[c] = s2acc;
}

// ---- overflow edges (expected count 0): full per-edge processing.
__global__ void k_ovf(const float* __restrict__ Xu, const float* __restrict__ CD,
                      const int* __restrict__ OV, const unsigned* __restrict__ ovfc,
                      float* __restrict__ L12, double* __restrict__ s1d,
                      double* __restrict__ s2d) {
    int n = (int)*ovfc; if (n > OCAP) n = OCAP;
    if (n == 0) return;
    const int gid = (blockIdx.x * blockDim.x + threadIdx.x) >> 4;
    const int ng = (gridDim.x * blockDim.x) >> 4;
    const int l = threadIdx.x & 15;
    for (int i = gid; i < n; i += ng) {
        const int* p = OV + (size_t)i * 6;
        int r = p[0], c = p[1], e = p[2];
        const float4* xu = (const float4*)(Xu + (size_t)r * EMB);
        const float4* cd = (const float4*)(CD + (size_t)c * 256);
        float4 x0 = xu[l], x1 = xu[l + 16];
        float4 cv0 = cd[l], cv1 = cd[l + 16];
        float4 dv0 = cd[l + 32], dv1 = cd[l + 48];
        float p1 = x0.x * cv0.x + x0.y * cv0.y + x0.z * cv0.z + x0.w * cv0.w
                 + x1.x * cv1.x + x1.y * cv1.y + x1.z * cv1.z + x1.w * cv1.w;
        float p2 = x0.x * dv0.x + x0.y * dv0.y + x0.z * dv0.z + x0.w * dv0.w
                 + x1.x * dv1.x + x1.y * dv1.y + x1.z * dv1.z + x1.w * dv1.w;
#pragma unroll
        for (int off = 1; off < 16; off <<= 1) {
            p1 += __shfl_xor(p1, off);
            p2 += __shfl_xor(p2, off);
        }
        if (l < 2) {
            float aP = __int_as_float(p[3]);
            float bP = __int_as_float((l == 0) ? p[4] : p[5]);
            float lg = fmaf(aP, (l == 0) ? p1 : p2, bP);
            double ev = dexp_fast(lg);
            L12[(size_t)e * 2 + l] = lg;
            if (l == 0) unsafeAtomicAdd(s1d + r, ev);
            else        unsafeAtomicAdd(s2d + c, ev);
        }
    }
}

// ---- ls = log2(sum) per row/col (float)
__global__ void k_ls(const double* __restrict__ s1d, const double* __restrict__ s2d,
                     float* __restrict__ ls1, float* __restrict__ ls2, int U, int I) {
    int i = blockIdx.x * blockDim.x + threadIdx.x;
    if (i >= U + I) return;
    double s = (i < U) ? s1d[i] : s2d[i - U];
    int ex;
    double m = frexp(s, &ex);
    float l2 = log2f((float)m) + (float)ex;
    if (i < U) ls1[i] = l2; else ls2[i - U] = l2;
}

// ---- final: pure f32, coalesced, 2 edges/thread
__global__ void k_fin4(const int* __restrict__ rows, const int* __restrict__ cols,
                       const float4* __restrict__ L12q,
                       const float* __restrict__ ls1, const float* __restrict__ ls2,
                       float* __restrict__ out, int nnz) {
    int i = blockIdx.x * blockDim.x + threadIdx.x, st = gridDim.x * blockDim.x;
    const int nq = nnz >> 1;
    const int2* rows2 = (const int2*)rows;
    const int2* cols2 = (const int2*)cols;
    for (int q = i; q < nq; q += st) {
        float4 lg = L12q[q];
        int2 r = rows2[q];
        int2 c = cols2[q];
        int e = q * 2;
        out[e]           = exp2f(fmaf(lg.x, LOG2E, -ls1[r.x]));
        out[e + 1]       = exp2f(fmaf(lg.z, LOG2E, -ls1[r.y]));
        out[nnz + e]     = exp2f(fmaf(lg.y, LOG2E, -ls2[c.x]));
        out[nnz + e + 1] = exp2f(fmaf(lg.w, LOG2E, -ls2[c.y]));
    }
    // odd tail
    if (i == 0 && (nnz & 1)) {
        int e = nnz - 1;
        const float2* L12 = (const float2*)L12q;
        float2 lg = L12[e];
        out[e]       = exp2f(fmaf(lg.x, LOG2E, -ls1[rows[e]]));
        out[nnz + e] = exp2f(fmaf(lg.y, LOG2E, -ls2[cols[e]]));
    }
}

// ================= fallback (unsorted, max-based) path =================
__global__ __launch_bounds__(256) void k_edge1(
    const float* __restrict__ Xu, const float* __restrict__ CD,
    const float2* __restrict__ t12, const float2* __restrict__ u12,
    const float* __restrict__ c0p, const float* __restrict__ adj,
    const float* __restrict__ gu1, const float* __restrict__ gu2,
    const int* __restrict__ rows, const int* __restrict__ cols,
    float* __restrict__ L1, float* __restrict__ L2,
    unsigned* __restrict__ mx1, unsigned* __restrict__ mx2, int nnz) {
    const int gid = blockIdx.x * 8 + (threadIdx.x >> 5);
    const int l = threadIdx.x & 31;
    const int stride = gridDim.x * 8;
    const float c0 = c0p[0];
    for (int e = gid; e < nnz; e += stride) {
        int r = rows[e], c = cols[e];
        float4 xu = ((const float4*)(Xu + (size_t)r * EMB))[l];
        const float4* cd = (const float4*)(CD + (size_t)c * 256);
        float4 cv = cd[l];
        float4 dv = cd[32 + l];
        float p1 = xu.x * cv.x + xu.y * cv.y + xu.z * cv.z + xu.w * cv.w;
        float p2 = xu.x * dv.x + xu.y * dv.y + xu.z * dv.z + xu.w * dv.w;
        for (int off = 16; off; off >>= 1) { p1 += __shfl_xor(p1, off); p2 += __shfl_xor(p2, off); }
        if (l < 2) {
            float p = (l == 0) ? p1 : p2;
            float2 tt = t12[r];
            float2 uu = u12[c];
            float tb = (l == 0) ? tt.x : tt.y;
            float ub = (l == 0) ? uu.x : uu.y;
            float g = logf(-logf(((l == 0) ? gu1 : gu2)[e]));
            float w = adj[e] * (p + tb + ub + c0);
            float lg = (w - g) * TAUINV;
            if (l == 0) { L1[e] = lg; atomicMax(mx1 + r, fkey(lg)); }
            else        { L2[e] = lg; atomicMax(mx2 + c, fkey(lg)); }
        }
    }
}

__global__ void k_sum(const int* __restrict__ rows, const int* __restrict__ cols,
                      const float* __restrict__ L1, const float* __restrict__ L2,
                      const unsigned* __restrict__ mx1, const unsigned* __restrict__ mx2,
                      float* __restrict__ s1, float* __restrict__ s2, int nnz) {
    int i = blockIdx.x * blockDim.x + threadIdx.x, st = gridDim.x * blockDim.x;
    for (int e = i; e < nnz; e += st) {
        int r = rows[e], c = cols[e];
        atomicAdd(s1 + r, expf(L1[e] - fdecode(mx1[r])));
        atomicAdd(s2 + c, expf(L2[e] - fdecode(mx2[c])));
    }
}

__global__ void k_fin2(const int* __restrict__ rows, const int* __restrict__ cols,
                       const float* __restrict__ L1, const float* __restrict__ L2,
                       const unsigned* __restrict__ mx1, const unsigned* __restrict__ mx2,
                       const float* __restrict__ s1, const float* __restrict__ s2,
                       float* __restrict__ out, int nnz) {
    int i = blockIdx.x * blockDim.x + threadIdx.x, st = gridDim.x * blockDim.x;
    for (int e = i; e < nnz; e += st) {
        int r = rows[e], c = cols[e];
        out[e]       = expf(L1[e] - fdecode(mx1[r])) / s1[r];
        out[nnz + e] = expf(L2[e] - fdecode(mx2[c])) / s2[c];
    }
}

extern "C" void kernel_launch(void* const* d_in, const int* in_sizes, int n_in,
                              void* d_out, int out_size, void* d_ws, size_t ws_size,
                              hipStream_t stream) {
    const float* Xu  = (const float*)d_in[0];
    const float* Xi  = (const float*)d_in[1];
    const float* Wq  = (const float*)d_in[2];
    const float* bq  = (const float*)d_in[3];
    const float* Wk  = (const float*)d_in[4];
    const float* bk  = (const float*)d_in[5];
    const float* adj = (const float*)d_in[6];
    const float* gu1 = (const float*)d_in[7];
    const float* gu2 = (const float*)d_in[8];
    const int* rows  = (const int*)d_in[9];
    const int* cols  = (const int*)d_in[10];
    float* out = (float*)d_out;

    const int U   = in_sizes[0] / EMB;
    const int I   = in_sizes[1] / EMB;
    const int nnz = in_sizes[6];

    char* w = (char*)d_ws;
    size_t off_b = 0;
    auto alloc = [&](size_t bytes) {
        char* p = w + off_b;
        off_b += (bytes + 15) & ~(size_t)15;
        return p;
    };

    float* BIGM = (float*)alloc(32768 * 4);
    float* v1   = (float*)alloc(128 * 4);
    float* v2   = (float*)alloc(128 * 4);
    float* c0   = (float*)alloc(64 * 4);      // [0]=c0, [1]=bias flag
    float2* t12 = (float2*)alloc((size_t)U * 8);
    float2* u12 = (float2*)alloc((size_t)I * 8);
    float* CD   = (float*)alloc((size_t)I * 256 * 4);
    float* L12  = (float*)alloc((size_t)nnz * 8);   // 2 floats per edge
    size_t base_need = off_b;
    // sorted-path extras: s1d + cnt + ovfc contiguous -> single memset
    double* s1d    = (double*)alloc((size_t)U * 8);
    unsigned* cnt  = (unsigned*)alloc((size_t)I * 4);
    unsigned* ovfc = (unsigned*)alloc(16 * 4);
    double* s2d    = (double*)alloc((size_t)I * 8);
    float* ls1     = (float*)alloc((size_t)U * 4);
    float* ls2     = (float*)alloc((size_t)I * 4);
    ix4* SA = (ix4*)alloc((size_t)I * CAP * 16);
    float* SB = (float*)alloc((size_t)I * CAP * 4);
    int* OV = (int*)alloc((size_t)OCAP * 24);
    size_t sorted_need = off_b;
    // fallback extras
    unsigned* mx1 = (unsigned*)alloc((size_t)U * 4);
    unsigned* mx2 = (unsigned*)alloc((size_t)I * 4);
    float* s1f  = (float*)alloc((size_t)U * 4);
    float* s2f  = (float*)alloc((size_t)I * 4);
    size_t fallback_need = off_b;

    const bool use_sorted = (sorted_need <= ws_size);
    if (!use_sorted && fallback_need > ws_size) return;

    k_prep<<<128, 128, 0, stream>>>(Wq, Wk, bq, bk, BIGM, v1, v2, c0);
    k_cd<<<(I + 31) / 32, 256, 0, stream>>>(Xi, BIGM, CD, I);
    k_rowdot2<<<(U + I + 7) / 8, 256, 0, stream>>>(Xu, Xi, U, I, v1, v2, t12, u12);

    if (use_sorted) {
        // zero s1d (U doubles) + cnt (I uints) + ovfc in one memset
        (void)hipMemsetAsync(s1d, 0, (size_t)U * 8 + (size_t)I * 4 + 64, stream);
        k_scatter_fc<<<2048, 256, 0, stream>>>(rows, cols, adj, gu1, gu2,
                                               t12, u12, c0, nnz, cnt, SA, SB,
                                               OV, ovfc);
        k_edge14<<<(I + 15) / 16, 256, 0, stream>>>(Xu, CD, cnt, SA, SB, L12,
                                                    s1d, s2d, I);
        k_ovf<<<64, 256, 0, stream>>>(Xu, CD, OV, ovfc, L12, s1d, s2d);
        k_ls<<<(U + I + 255) / 256, 256, 0, stream>>>(s1d, s2d, ls1, ls2, U, I);
        k_fin4<<<2048, 256, 0, stream>>>(rows, cols, (const float4*)L12, ls1, ls2,
                                         out, nnz);
    } else {
        float* L1 = (float*)L12;
        float* L2 = L1 + nnz;
        (void)hipMemsetAsync(mx1, 0, (size_t)(2 * (U + I)) * 4, stream);
        k_edge1<<<4096, 256, 0, stream>>>(Xu, CD, t12, u12, c0, adj, gu1, gu2,
                                          rows, cols, L1, L2, mx1, mx2, nnz);
        k_sum<<<2048, 256, 0, stream>>>(rows, cols, L1, L2, mx1, mx2, s1f, s2f, nnz);
        k_fin2<<<2048, 256, 0, stream>>>(rows, cols, L1, L2, mx1, mx2, s1f, s2f,
                                         out, nnz);
    }
}

// Round 18
// 358.955 us; speedup vs baseline: 1.1730x; 1.1730x over previous
//
#include <hip/hip_runtime.h>
#include <hip/hip_bf16.h>

// Sparse graph-attention Gumbel mask.
//
// With M = Wq^T Wk [E,E]:
//   w_ui[e] = adj*( Xu[r]·C[c] + t1[r] + u1[c] + c0 ),  C = Xi M^T
//   w_iu[e] = adj*( Xu[r]·D[c] + t2[r] + u2[c] + c0 ),  D = Xi M
//
// R18 = R16 exactly (fixed-capacity c-binning, bin-per-16-lane-group edge
// kernel, no-max f64 softmax via fast exp, lane0/1 tail split, f32 final
// pass; R17's NT stores + 2-wide fin REVERTED as regressions), with ONE
// change: k_cd (compute-heavy) and k_scatter (memory-heavy, independent)
// are FUSED into one launch with disjoint block ranges so the hardware
// overlaps them (stream serializes separate launches; events are banned).

#define EMB 128
#define TAUINV 2.0f
#define LOG2E 1.44269504f
#define CAP 128
#define OCAP 65536
#define NSCAT 2048

__device__ __forceinline__ unsigned fkey(float f) {
    unsigned u = __float_as_uint(f);
    return (u & 0x80000000u) ? ~u : (u | 0x80000000u);
}
__device__ __forceinline__ float fdecode(unsigned u) {
    return __uint_as_float((u & 0x80000000u) ? (u ^ 0x80000000u) : ~u);
}

// exp(lg) as double without overflow: exp2f fraction + ldexp integer part.
__device__ __forceinline__ double dexp_fast(float lg) {
    float t = lg * LOG2E;
    float kf = floorf(t);
    float f = exp2f(t - kf);
    return ldexp((double)f, (int)kf);
}

// ---- BIGM[k][j] (j<128: M[j][k]; j>=128: M[k][j-128]), v1, v2, c0, flag
__global__ void k_prep(const float* __restrict__ Wq, const float* __restrict__ Wk,
                       const float* __restrict__ bq, const float* __restrict__ bk,
                       float* __restrict__ BIGM, float* __restrict__ v1,
                       float* __restrict__ v2, float* __restrict__ c0) {
    int e1 = blockIdx.x, e2 = threadIdx.x;
    float acc = 0.f;
    for (int a = 0; a < EMB; ++a) acc += Wq[a * EMB + e1] * Wk[a * EMB + e2];
    BIGM[e2 * 256 + e1] = acc;
    BIGM[e1 * 256 + 128 + e2] = acc;
    if (e2 == 0) { float s = 0.f; for (int a = 0; a < EMB; ++a) s += Wq[a * EMB + e1] * bk[a]; v1[e1] = s; }
    if (e2 == 1) { float s = 0.f; for (int a = 0; a < EMB; ++a) s += Wk[a * EMB + e1] * bq[a]; v2[e1] = s; }
    if (e1 == 0 && e2 == 2) { float s = 0.f; for (int a = 0; a < EMB; ++a) s += bq[a] * bk[a]; c0[0] = s; }
    if (e1 == 0 && e2 == 3) { float s = 0.f; for (int a = 0; a < EMB; ++a) s += fabsf(bq[a]) + fabsf(bk[a]); c0[1] = s; }
}

// ---- fused rowdots, packed: t12[r]={Xu.v1,Xu.v2}, u12[c]={Xi.v2,Xi.v1}
__global__ void k_rowdot2(const float* __restrict__ Xu, const float* __restrict__ Xi,
                          int U, int I,
                          const float* __restrict__ v1, const float* __restrict__ v2,
                          float2* __restrict__ t12, float2* __restrict__ u12) {
    int g = blockIdx.x * 8 + (threadIdx.x >> 5);
    int l = threadIdx.x & 31;
    if (g >= U + I) return;
    const float* X = (g < U) ? (Xu + (size_t)g * EMB) : (Xi + (size_t)(g - U) * EMB);
    float4 x = ((const float4*)X)[l];
    float4 av = ((const float4*)v1)[l];
    float4 bv = ((const float4*)v2)[l];
    float pa = x.x * av.x + x.y * av.y + x.z * av.z + x.w * av.w;
    float pb = x.x * bv.x + x.y * bv.y + x.z * bv.z + x.w * bv.w;
    for (int off = 16; off; off >>= 1) { pa += __shfl_xor(pa, off); pb += __shfl_xor(pb, off); }
    if (l == 0) {
        if (g < U) t12[g] = make_float2(pa, pb);
        else       u12[g - U] = make_float2(pb, pa);
    }
}

// ---- FUSED: blocks [0,nbCD) = CD GEMM; blocks [nbCD, nbCD+NSCAT) = scatter
__global__ __launch_bounds__(256) void k_mid(
    const float* __restrict__ Xi, const float* __restrict__ BIGM,
    float* __restrict__ CD, int nItems, int nbCD,
    const int* __restrict__ rows, const int* __restrict__ cols,
    const float* __restrict__ adj, const float* __restrict__ gu1,
    const float* __restrict__ gu2,
    const float2* __restrict__ t12, const float2* __restrict__ u12,
    const float* __restrict__ c0p, int nnz,
    unsigned* __restrict__ cnt, int4* __restrict__ SA,
    float* __restrict__ SB, int* __restrict__ OV,
    unsigned* __restrict__ ovfc) {
    __shared__ float Xs[32][EMB];
    __shared__ float Ms[32][256];
    if (blockIdx.x < (unsigned)nbCD) {
        // ======== CD GEMM body (identical math to R16 k_cd) ========
        const int t = threadIdx.x;
        const int m0 = blockIdx.x * 32;

        const float4* Xi4 = (const float4*)Xi;
        float4* Xs4 = (float4*)Xs;
        for (int idx = t; idx < 32 * 32; idx += 256) {
            int r = idx >> 5, c = idx & 31;
            int row = m0 + r;
            Xs4[idx] = (row < nItems) ? Xi4[(size_t)row * 32 + c]
                                      : make_float4(0.f, 0.f, 0.f, 0.f);
        }

        const int tc = t & 63;
        const int tr = t >> 6;
        float4 acc[8] = {};

        const float4* BG4 = (const float4*)BIGM;
        float4* Ms4 = (float4*)Ms;
        for (int kc = 0; kc < EMB; kc += 32) {
            __syncthreads();
            for (int idx = t; idx < 32 * 64; idx += 256)
                Ms4[idx] = BG4[(size_t)(kc + (idx >> 6)) * 64 + (idx & 63)];
            __syncthreads();
#pragma unroll
            for (int kk = 0; kk < 32; ++kk) {
                float4 w = Ms4[kk * 64 + tc];
#pragma unroll
                for (int i = 0; i < 8; ++i) {
                    float x = Xs[tr * 8 + i][kc + kk];
                    acc[i].x += x * w.x; acc[i].y += x * w.y;
                    acc[i].z += x * w.z; acc[i].w += x * w.w;
                }
            }
        }
#pragma unroll
        for (int i = 0; i < 8; ++i) {
            int row = m0 + tr * 8 + i;
            if (row < nItems)
                ((float4*)(CD + (size_t)row * 256))[tc] = acc[i];
        }
    } else {
        // ======== scatter body (identical math to R16 k_scatter_fc) ========
        const float c0 = c0p[0];
        const bool useb = (c0p[1] != 0.f);
        int i = (blockIdx.x - nbCD) * blockDim.x + threadIdx.x;
        int st = NSCAT * blockDim.x;
        for (int e = i; e < nnz; e += st) {
            int r = rows[e], c = cols[e];
            unsigned pos = atomicAdd(&cnt[c], 1u);
            float a = adj[e];
            float g1 = logf(-logf(gu1[e]));   // logf: u near 1 needs rel accuracy
            float g2 = logf(-logf(gu2[e]));
            float b1 = -g1 * TAUINV;
            float b2 = -g2 * TAUINV;
            if (useb) {
                float2 tt = t12[r];
                float2 uu = u12[c];
                b1 += a * (tt.x + uu.x + c0) * TAUINV;
                b2 += a * (tt.y + uu.y + c0) * TAUINV;
            }
            if (pos < CAP) {
                size_t s = (size_t)c * CAP + pos;
                SA[s] = make_int4(r, e, __float_as_int(a * TAUINV), __float_as_int(b1));
                SB[s] = b2;
            } else {
                unsigned o = atomicAdd(ovfc, 1u);
                if (o < OCAP) {
                    int* p = OV + (size_t)o * 6;
                    p[0] = r; p[1] = c; p[2] = e;
                    p[3] = __float_as_int(a * TAUINV);
                    p[4] = __float_as_int(b1); p[5] = __float_as_int(b2);
                }
            }
        }
    }
}

// ---- edge kernel: one bin per 16-lane group; CD register-held; lane0/1
// tail split with fast exp; s2 plain store (unique c per group).
__global__ __launch_bounds__(256) void k_edge14(
    const float* __restrict__ Xu, const float* __restrict__ CD,
    const unsigned* __restrict__ cnt, const int4* __restrict__ SA,
    const float* __restrict__ SB,
    float2* __restrict__ L12, double* __restrict__ s1d, double* __restrict__ s2d,
    int I) {
    const int g = threadIdx.x >> 4, l = threadIdx.x & 15;
    const int c = blockIdx.x * 16 + g;
    if (c >= I) return;
    unsigned n = cnt[c]; if (n > CAP) n = CAP;
    if (n == 0) return;
    const unsigned lo = (unsigned)c * CAP;
    const unsigned hi = lo + n;
    const float4* cd = (const float4*)(CD + (size_t)c * 256);
    const float4 cv0 = cd[l], cv1 = cd[l + 16];
    const float4 dv0 = cd[l + 32], dv1 = cd[l + 48];
    double s2acc = 0.0;
    for (unsigned j = lo; j < hi; ++j) {
        int4 m = SA[j];
        float b2s = SB[j];
        const float4* xu = (const float4*)(Xu + (size_t)m.x * EMB);
        float4 x0 = xu[l], x1 = xu[l + 16];
        float p1 = x0.x * cv0.x + x0.y * cv0.y + x0.z * cv0.z + x0.w * cv0.w
                 + x1.x * cv1.x + x1.y * cv1.y + x1.z * cv1.z + x1.w * cv1.w;
        float p2 = x0.x * dv0.x + x0.y * dv0.y + x0.z * dv0.z + x0.w * dv0.w
                 + x1.x * dv1.x + x1.y * dv1.y + x1.z * dv1.z + x1.w * dv1.w;
#pragma unroll
        for (int off = 1; off < 16; off <<= 1) {
            p1 += __shfl_xor(p1, off);
            p2 += __shfl_xor(p2, off);
        }
        if (l < 2) {
            float aP = __int_as_float(m.z);
            float bP = (l == 0) ? __int_as_float(m.w) : b2s;
            float lg = fmaf(aP, (l == 0) ? p1 : p2, bP);
            double ev = dexp_fast(lg);
            ((float*)(L12 + m.y))[l] = lg;
            if (l == 0) unsafeAtomicAdd(s1d + m.x, ev);
            else        s2acc += ev;
        }
    }
    if (l == 1) s2d[c] = s2acc;
}

// ---- overflow edges (expected count 0): full per-edge processing.
__global__ void k_ovf(const float* __restrict__ Xu, const float* __restrict__ CD,
                      const int* __restrict__ OV, const unsigned* __restrict__ ovfc,
                      float2* __restrict__ L12, double* __restrict__ s1d,
                      double* __restrict__ s2d) {
    int n = (int)*ovfc; if (n > OCAP) n = OCAP;
    if (n == 0) return;
    const int gid = (blockIdx.x * blockDim.x + threadIdx.x) >> 4;
    const int ng = (gridDim.x * blockDim.x) >> 4;
    const int l = threadIdx.x & 15;
    for (int i = gid; i < n; i += ng) {
        const int* p = OV + (size_t)i * 6;
        int r = p[0], c = p[1], e = p[2];
        const float4* xu = (const float4*)(Xu + (size_t)r * EMB);
        const float4* cd = (const float4*)(CD + (size_t)c * 256);
        float4 x0 = xu[l], x1 = xu[l + 16];
        float4 cv0 = cd[l], cv1 = cd[l + 16];
        float4 dv0 = cd[l + 32], dv1 = cd[l + 48];
        float p1 = x0.x * cv0.x + x0.y * cv0.y + x0.z * cv0.z + x0.w * cv0.w
                 + x1.x * cv1.x + x1.y * cv1.y + x1.z * cv1.z + x1.w * cv1.w;
        float p2 = x0.x * dv0.x + x0.y * dv0.y + x0.z * dv0.z + x0.w * dv0.w
                 + x1.x * dv1.x + x1.y * dv1.y + x1.z * dv1.z + x1.w * dv1.w;
#pragma unroll
        for (int off = 1; off < 16; off <<= 1) {
            p1 += __shfl_xor(p1, off);
            p2 += __shfl_xor(p2, off);
        }
        if (l < 2) {
            float aP = __int_as_float(p[3]);
            float bP = __int_as_float((l == 0) ? p[4] : p[5]);
            float lg = fmaf(aP, (l == 0) ? p1 : p2, bP);
            double ev = dexp_fast(lg);
            ((float*)(L12 + e))[l] = lg;
            if (l == 0) unsafeAtomicAdd(s1d + r, ev);
            else        unsafeAtomicAdd(s2d + c, ev);
        }
    }
}

// ---- ls = log2(sum) per row/col (float)
__global__ void k_ls(const double* __restrict__ s1d, const double* __restrict__ s2d,
                     float* __restrict__ ls1, float* __restrict__ ls2, int U, int I) {
    int i = blockIdx.x * blockDim.x + threadIdx.x;
    if (i >= U + I) return;
    double s = (i < U) ? s1d[i] : s2d[i - U];
    int ex;
    double m = frexp(s, &ex);
    float l2 = log2f((float)m) + (float)ex;
    if (i < U) ls1[i] = l2; else ls2[i - U] = l2;
}

// ---- final: pure f32, coalesced; out = exp2(lg*log2e - log2(sum))
__global__ void k_fin4(const int* __restrict__ rows, const int* __restrict__ cols,
                       const float2* __restrict__ L12,
                       const float* __restrict__ ls1, const float* __restrict__ ls2,
                       float* __restrict__ out, int nnz) {
    int i = blockIdx.x * blockDim.x + threadIdx.x, st = gridDim.x * blockDim.x;
    for (int e = i; e < nnz; e += st) {
        float2 lg = L12[e];
        out[e]       = exp2f(fmaf(lg.x, LOG2E, -ls1[rows[e]]));
        out[nnz + e] = exp2f(fmaf(lg.y, LOG2E, -ls2[cols[e]]));
    }
}

// ================= fallback (unsorted, max-based) path =================
__global__ __launch_bounds__(256) void k_cd(const float* __restrict__ Xi,
                                            const float* __restrict__ BIGM,
                                            float* __restrict__ CD, int nItems) {
    __shared__ float Xs[32][EMB];
    __shared__ float Ms[32][256];
    const int t = threadIdx.x;
    const int m0 = blockIdx.x * 32;
    const float4* Xi4 = (const float4*)Xi;
    float4* Xs4 = (float4*)Xs;
    for (int idx = t; idx < 32 * 32; idx += 256) {
        int r = idx >> 5, c = idx & 31;
        int row = m0 + r;
        Xs4[idx] = (row < nItems) ? Xi4[(size_t)row * 32 + c]
                                  : make_float4(0.f, 0.f, 0.f, 0.f);
    }
    const int tc = t & 63;
    const int tr = t >> 6;
    float4 acc[8] = {};
    const float4* BG4 = (const float4*)BIGM;
    float4* Ms4 = (float4*)Ms;
    for (int kc = 0; kc < EMB; kc += 32) {
        __syncthreads();
        for (int idx = t; idx < 32 * 64; idx += 256)
            Ms4[idx] = BG4[(size_t)(kc + (idx >> 6)) * 64 + (idx & 63)];
        __syncthreads();
#pragma unroll
        for (int kk = 0; kk < 32; ++kk) {
            float4 w = Ms4[kk * 64 + tc];
#pragma unroll
            for (int i = 0; i < 8; ++i) {
                float x = Xs[tr * 8 + i][kc + kk];
                acc[i].x += x * w.x; acc[i].y += x * w.y;
                acc[i].z += x * w.z; acc[i].w += x * w.w;
            }
        }
    }
#pragma unroll
    for (int i = 0; i < 8; ++i) {
        int row = m0 + tr * 8 + i;
        if (row < nItems)
            ((float4*)(CD + (size_t)row * 256))[tc] = acc[i];
    }
}

__global__ __launch_bounds__(256) void k_edge1(
    const float* __restrict__ Xu, const float* __restrict__ CD,
    const float2* __restrict__ t12, const float2* __restrict__ u12,
    const float* __restrict__ c0p, const float* __restrict__ adj,
    const float* __restrict__ gu1, const float* __restrict__ gu2,
    const int* __restrict__ rows, const int* __restrict__ cols,
    float* __restrict__ L1, float* __restrict__ L2,
    unsigned* __restrict__ mx1, unsigned* __restrict__ mx2, int nnz) {
    const int gid = blockIdx.x * 8 + (threadIdx.x >> 5);
    const int l = threadIdx.x & 31;
    const int stride = gridDim.x * 8;
    const float c0 = c0p[0];
    for (int e = gid; e < nnz; e += stride) {
        int r = rows[e], c = cols[e];
        float4 xu = ((const float4*)(Xu + (size_t)r * EMB))[l];
        const float4* cd = (const float4*)(CD + (size_t)c * 256);
        float4 cv = cd[l];
        float4 dv = cd[32 + l];
        float p1 = xu.x * cv.x + xu.y * cv.y + xu.z * cv.z + xu.w * cv.w;
        float p2 = xu.x * dv.x + xu.y * dv.y + xu.z * dv.z + xu.w * dv.w;
        for (int off = 16; off; off >>= 1) { p1 += __shfl_xor(p1, off); p2 += __shfl_xor(p2, off); }
        if (l < 2) {
            float p = (l == 0) ? p1 : p2;
            float2 tt = t12[r];
            float2 uu = u12[c];
            float tb = (l == 0) ? tt.x : tt.y;
            float ub = (l == 0) ? uu.x : uu.y;
            float g = logf(-logf(((l == 0) ? gu1 : gu2)[e]));
            float w = adj[e] * (p + tb + ub + c0);
            float lg = (w - g) * TAUINV;
            if (l == 0) { L1[e] = lg; atomicMax(mx1 + r, fkey(lg)); }
            else        { L2[e] = lg; atomicMax(mx2 + c, fkey(lg)); }
        }
    }
}

__global__ void k_sum(const int* __restrict__ rows, const int* __restrict__ cols,
                      const float* __restrict__ L1, const float* __restrict__ L2,
                      const unsigned* __restrict__ mx1, const unsigned* __restrict__ mx2,
                      float* __restrict__ s1, float* __restrict__ s2, int nnz) {
    int i = blockIdx.x * blockDim.x + threadIdx.x, st = gridDim.x * blockDim.x;
    for (int e = i; e < nnz; e += st) {
        int r = rows[e], c = cols[e];
        atomicAdd(s1 + r, expf(L1[e] - fdecode(mx1[r])));
        atomicAdd(s2 + c, expf(L2[e] - fdecode(mx2[c])));
    }
}

__global__ void k_fin2(const int* __restrict__ rows, const int* __restrict__ cols,
                       const float* __restrict__ L1, const float* __restrict__ L2,
                       const unsigned* __restrict__ mx1, const unsigned* __restrict__ mx2,
                       const float* __restrict__ s1, const float* __restrict__ s2,
                       float* __restrict__ out, int nnz) {
    int i = blockIdx.x * blockDim.x + threadIdx.x, st = gridDim.x * blockDim.x;
    for (int e = i; e < nnz; e += st) {
        int r = rows[e], c = cols[e];
        out[e]       = expf(L1[e] - fdecode(mx1[r])) / s1[r];
        out[nnz + e] = expf(L2[e] - fdecode(mx2[c])) / s2[c];
    }
}

extern "C" void kernel_launch(void* const* d_in, const int* in_sizes, int n_in,
                              void* d_out, int out_size, void* d_ws, size_t ws_size,
                              hipStream_t stream) {
    const float* Xu  = (const float*)d_in[0];
    const float* Xi  = (const float*)d_in[1];
    const float* Wq  = (const float*)d_in[2];
    const float* bq  = (const float*)d_in[3];
    const float* Wk  = (const float*)d_in[4];
    const float* bk  = (const float*)d_in[5];
    const float* adj = (const float*)d_in[6];
    const float* gu1 = (const float*)d_in[7];
    const float* gu2 = (const float*)d_in[8];
    const int* rows  = (const int*)d_in[9];
    const int* cols  = (const int*)d_in[10];
    float* out = (float*)d_out;

    const int U   = in_sizes[0] / EMB;
    const int I   = in_sizes[1] / EMB;
    const int nnz = in_sizes[6];
    const int nbCD = (I + 31) / 32;

    char* w = (char*)d_ws;
    size_t off_b = 0;
    auto alloc = [&](size_t bytes) {
        char* p = w + off_b;
        off_b += (bytes + 15) & ~(size_t)15;
        return p;
    };

    float* BIGM = (float*)alloc(32768 * 4);
    float* v1   = (float*)alloc(128 * 4);
    float* v2   = (float*)alloc(128 * 4);
    float* c0   = (float*)alloc(64 * 4);      // [0]=c0, [1]=bias flag
    float2* t12 = (float2*)alloc((size_t)U * 8);
    float2* u12 = (float2*)alloc((size_t)I * 8);
    float* CD   = (float*)alloc((size_t)I * 256 * 4);
    float2* L12 = (float2*)alloc((size_t)nnz * 8);
    size_t base_need = off_b;
    // sorted-path extras: s1d + cnt + ovfc contiguous -> single memset
    double* s1d    = (double*)alloc((size_t)U * 8);
    unsigned* cnt  = (unsigned*)alloc((size_t)I * 4);
    unsigned* ovfc = (unsigned*)alloc(16 * 4);
    double* s2d    = (double*)alloc((size_t)I * 8);
    float* ls1     = (float*)alloc((size_t)U * 4);
    float* ls2     = (float*)alloc((size_t)I * 4);
    int4* SA = (int4*)alloc((size_t)I * CAP * 16);
    float* SB = (float*)alloc((size_t)I * CAP * 4);
    int* OV = (int*)alloc((size_t)OCAP * 24);
    size_t sorted_need = off_b;
    // fallback extras
    unsigned* mx1 = (unsigned*)alloc((size_t)U * 4);
    unsigned* mx2 = (unsigned*)alloc((size_t)I * 4);
    float* s1f  = (float*)alloc((size_t)U * 4);
    float* s2f  = (float*)alloc((size_t)I * 4);
    size_t fallback_need = off_b;

    const bool use_sorted = (sorted_need <= ws_size);
    if (!use_sorted && fallback_need > ws_size) return;

    k_prep<<<128, 128, 0, stream>>>(Wq, Wk, bq, bk, BIGM, v1, v2, c0);
    k_rowdot2<<<(U + I + 7) / 8, 256, 0, stream>>>(Xu, Xi, U, I, v1, v2, t12, u12);

    if (use_sorted) {
        // zero s1d (U doubles) + cnt (I uints) + ovfc in one memset
        (void)hipMemsetAsync(s1d, 0, (size_t)U * 8 + (size_t)I * 4 + 64, stream);
        k_mid<<<nbCD + NSCAT, 256, 0, stream>>>(Xi, BIGM, CD, I, nbCD,
                                                rows, cols, adj, gu1, gu2,
                                                t12, u12, c0, nnz, cnt, SA, SB,
                                                OV, ovfc);
        k_edge14<<<(I + 15) / 16, 256, 0, stream>>>(Xu, CD, cnt, SA, SB, L12,
                                                    s1d, s2d, I);
        k_ovf<<<64, 256, 0, stream>>>(Xu, CD, OV, ovfc, L12, s1d, s2d);
        k_ls<<<(U + I + 255) / 256, 256, 0, stream>>>(s1d, s2d, ls1, ls2, U, I);
        k_fin4<<<2048, 256, 0, stream>>>(rows, cols, L12, ls1, ls2, out, nnz);
    } else {
        float* L1 = (float*)L12;
        float* L2 = L1 + nnz;
        (void)hipMemsetAsync(mx1, 0, (size_t)(2 * (U + I)) * 4, stream);
        k_cd<<<nbCD, 256, 0, stream>>>(Xi, BIGM, CD, I);
        k_edge1<<<4096, 256, 0, stream>>>(Xu, CD, t12, u12, c0, adj, gu1, gu2,
                                          rows, cols, L1, L2, mx1, mx2, nnz);
        k_sum<<<2048, 256, 0, stream>>>(rows, cols, L1, L2, mx1, mx2, s1f, s2f, nnz);
        k_fin2<<<2048, 256, 0, stream>>>(rows, cols, L1, L2, mx1, mx2, s1f, s2f,
                                         out, nnz);
    }
}

// Round 19
// 335.441 us; speedup vs baseline: 1.2552x; 1.0701x over previous
//
#include <hip/hip_runtime.h>
#include <hip/hip_bf16.h>
#include <hip/hip_fp16.h>

// Sparse graph-attention Gumbel mask.
//
// With M = Wq^T Wk [E,E]:
//   w_ui[e] = adj*( Xu[r]·C[c] + t1[r] + u1[c] + c0 ),  C = Xi M^T
//   w_iu[e] = adj*( Xu[r]·D[c] + t2[r] + u2[c] + c0 ),  D = Xi M
//
// R19 = R18 (fixed-cap c-binning, fused cd+scatter k_mid, bin-per-16-lane
// edge kernel, no-max f64 softmax) with:
//  - SB eliminated: (b1,b2) packed as half2 into SA.w -> ONE 16B scattered
//    store per edge (halves scatter write-allocate RMW lines). f16 error
//    on b <= ~0.009 logit -> ~1% out, within 2e-2 threshold.
//  - k_ls dropped: fin divides in f64 against hot s1d/s2d directly.
//  - rowdot2 early-exits when biases are all-zero (flag from k_prep).

#define EMB 128
#define TAUINV 2.0f
#define LOG2E 1.44269504f
#define CAP 128
#define OCAP 65536
#define NSCAT 2048

__device__ __forceinline__ unsigned fkey(float f) {
    unsigned u = __float_as_uint(f);
    return (u & 0x80000000u) ? ~u : (u | 0x80000000u);
}
__device__ __forceinline__ float fdecode(unsigned u) {
    return __uint_as_float((u & 0x80000000u) ? (u ^ 0x80000000u) : ~u);
}

// exp(lg) as double without overflow: exp2f fraction + ldexp integer part.
__device__ __forceinline__ double dexp_fast(float lg) {
    float t = lg * LOG2E;
    float kf = floorf(t);
    float f = exp2f(t - kf);
    return ldexp((double)f, (int)kf);
}

// ---- BIGM[k][j] (j<128: M[j][k]; j>=128: M[k][j-128]), v1, v2, c0, flag
__global__ void k_prep(const float* __restrict__ Wq, const float* __restrict__ Wk,
                       const float* __restrict__ bq, const float* __restrict__ bk,
                       float* __restrict__ BIGM, float* __restrict__ v1,
                       float* __restrict__ v2, float* __restrict__ c0) {
    int e1 = blockIdx.x, e2 = threadIdx.x;
    float acc = 0.f;
    for (int a = 0; a < EMB; ++a) acc += Wq[a * EMB + e1] * Wk[a * EMB + e2];
    BIGM[e2 * 256 + e1] = acc;
    BIGM[e1 * 256 + 128 + e2] = acc;
    if (e2 == 0) { float s = 0.f; for (int a = 0; a < EMB; ++a) s += Wq[a * EMB + e1] * bk[a]; v1[e1] = s; }
    if (e2 == 1) { float s = 0.f; for (int a = 0; a < EMB; ++a) s += Wk[a * EMB + e1] * bq[a]; v2[e1] = s; }
    if (e1 == 0 && e2 == 2) { float s = 0.f; for (int a = 0; a < EMB; ++a) s += bq[a] * bk[a]; c0[0] = s; }
    if (e1 == 0 && e2 == 3) { float s = 0.f; for (int a = 0; a < EMB; ++a) s += fabsf(bq[a]) + fabsf(bk[a]); c0[1] = s; }
}

// ---- fused rowdots (skipped entirely when biases are zero)
__global__ void k_rowdot2(const float* __restrict__ Xu, const float* __restrict__ Xi,
                          int U, int I,
                          const float* __restrict__ v1, const float* __restrict__ v2,
                          const float* __restrict__ c0p,
                          float2* __restrict__ t12, float2* __restrict__ u12) {
    if (c0p[1] == 0.f) return;   // all biases zero -> t12/u12 never read
    int g = blockIdx.x * 8 + (threadIdx.x >> 5);
    int l = threadIdx.x & 31;
    if (g >= U + I) return;
    const float* X = (g < U) ? (Xu + (size_t)g * EMB) : (Xi + (size_t)(g - U) * EMB);
    float4 x = ((const float4*)X)[l];
    float4 av = ((const float4*)v1)[l];
    float4 bv = ((const float4*)v2)[l];
    float pa = x.x * av.x + x.y * av.y + x.z * av.z + x.w * av.w;
    float pb = x.x * bv.x + x.y * bv.y + x.z * bv.z + x.w * bv.w;
    for (int off = 16; off; off >>= 1) { pa += __shfl_xor(pa, off); pb += __shfl_xor(pb, off); }
    if (l == 0) {
        if (g < U) t12[g] = make_float2(pa, pb);
        else       u12[g - U] = make_float2(pb, pa);
    }
}

// ---- FUSED: blocks [0,nbCD) = CD GEMM; blocks [nbCD, nbCD+NSCAT) = scatter
__global__ __launch_bounds__(256) void k_mid(
    const float* __restrict__ Xi, const float* __restrict__ BIGM,
    float* __restrict__ CD, int nItems, int nbCD,
    const int* __restrict__ rows, const int* __restrict__ cols,
    const float* __restrict__ adj, const float* __restrict__ gu1,
    const float* __restrict__ gu2,
    const float2* __restrict__ t12, const float2* __restrict__ u12,
    const float* __restrict__ c0p, int nnz,
    unsigned* __restrict__ cnt, int4* __restrict__ SA,
    int* __restrict__ OV, unsigned* __restrict__ ovfc) {
    __shared__ float Xs[32][EMB];
    __shared__ float Ms[32][256];
    if (blockIdx.x < (unsigned)nbCD) {
        // ======== CD GEMM body ========
        const int t = threadIdx.x;
        const int m0 = blockIdx.x * 32;

        const float4* Xi4 = (const float4*)Xi;
        float4* Xs4 = (float4*)Xs;
        for (int idx = t; idx < 32 * 32; idx += 256) {
            int r = idx >> 5, c = idx & 31;
            int row = m0 + r;
            Xs4[idx] = (row < nItems) ? Xi4[(size_t)row * 32 + c]
                                      : make_float4(0.f, 0.f, 0.f, 0.f);
        }

        const int tc = t & 63;
        const int tr = t >> 6;
        float4 acc[8] = {};

        const float4* BG4 = (const float4*)BIGM;
        float4* Ms4 = (float4*)Ms;
        for (int kc = 0; kc < EMB; kc += 32) {
            __syncthreads();
            for (int idx = t; idx < 32 * 64; idx += 256)
                Ms4[idx] = BG4[(size_t)(kc + (idx >> 6)) * 64 + (idx & 63)];
            __syncthreads();
#pragma unroll
            for (int kk = 0; kk < 32; ++kk) {
                float4 w = Ms4[kk * 64 + tc];
#pragma unroll
                for (int i = 0; i < 8; ++i) {
                    float x = Xs[tr * 8 + i][kc + kk];
                    acc[i].x += x * w.x; acc[i].y += x * w.y;
                    acc[i].z += x * w.z; acc[i].w += x * w.w;
                }
            }
        }
#pragma unroll
        for (int i = 0; i < 8; ++i) {
            int row = m0 + tr * 8 + i;
            if (row < nItems)
                ((float4*)(CD + (size_t)row * 256))[tc] = acc[i];
        }
    } else {
        // ======== scatter body: ONE 16B store per edge ========
        const float c0 = c0p[0];
        const bool useb = (c0p[1] != 0.f);
        int i = (blockIdx.x - nbCD) * blockDim.x + threadIdx.x;
        int st = NSCAT * blockDim.x;
        for (int e = i; e < nnz; e += st) {
            int r = rows[e], c = cols[e];
            unsigned pos = atomicAdd(&cnt[c], 1u);
            float a = adj[e];
            float g1 = logf(-logf(gu1[e]));   // logf: u near 1 needs rel accuracy
            float g2 = logf(-logf(gu2[e]));
            float b1 = -g1 * TAUINV;
            float b2 = -g2 * TAUINV;
            if (useb) {
                float2 tt = t12[r];
                float2 uu = u12[c];
                b1 += a * (tt.x + uu.x + c0) * TAUINV;
                b2 += a * (tt.y + uu.y + c0) * TAUINV;
            }
            if (pos < CAP) {
                __half2 hb = __floats2half2_rn(b1, b2);
                SA[(size_t)c * CAP + pos] =
                    make_int4(r, e, __float_as_int(a * TAUINV),
                              *(const int*)&hb);
            } else {
                unsigned o = atomicAdd(ovfc, 1u);
                if (o < OCAP) {
                    int* p = OV + (size_t)o * 6;
                    p[0] = r; p[1] = c; p[2] = e;
                    p[3] = __float_as_int(a * TAUINV);
                    p[4] = __float_as_int(b1); p[5] = __float_as_int(b2);
                }
            }
        }
    }
}

// ---- edge kernel: one bin per 16-lane group; CD register-held; lane0/1
// tail split with fast exp; s2 plain store (unique c per group).
__global__ __launch_bounds__(256) void k_edge14(
    const float* __restrict__ Xu, const float* __restrict__ CD,
    const unsigned* __restrict__ cnt, const int4* __restrict__ SA,
    float2* __restrict__ L12, double* __restrict__ s1d, double* __restrict__ s2d,
    int I) {
    const int g = threadIdx.x >> 4, l = threadIdx.x & 15;
    const int c = blockIdx.x * 16 + g;
    if (c >= I) return;
    unsigned n = cnt[c]; if (n > CAP) n = CAP;
    if (n == 0) return;
    const unsigned lo = (unsigned)c * CAP;
    const unsigned hi = lo + n;
    const float4* cd = (const float4*)(CD + (size_t)c * 256);
    const float4 cv0 = cd[l], cv1 = cd[l + 16];
    const float4 dv0 = cd[l + 32], dv1 = cd[l + 48];
    double s2acc = 0.0;
    for (unsigned j = lo; j < hi; ++j) {
        int4 m = SA[j];
        const float4* xu = (const float4*)(Xu + (size_t)m.x * EMB);
        float4 x0 = xu[l], x1 = xu[l + 16];
        float p1 = x0.x * cv0.x + x0.y * cv0.y + x0.z * cv0.z + x0.w * cv0.w
                 + x1.x * cv1.x + x1.y * cv1.y + x1.z * cv1.z + x1.w * cv1.w;
        float p2 = x0.x * dv0.x + x0.y * dv0.y + x0.z * dv0.z + x0.w * dv0.w
                 + x1.x * dv1.x + x1.y * dv1.y + x1.z * dv1.z + x1.w * dv1.w;
#pragma unroll
        for (int off = 1; off < 16; off <<= 1) {
            p1 += __shfl_xor(p1, off);
            p2 += __shfl_xor(p2, off);
        }
        if (l < 2) {
            __half2 hb = *(const __half2*)&m.w;
            float aP = __int_as_float(m.z);
            float bP = (l == 0) ? __low2float(hb) : __high2float(hb);
            float lg = fmaf(aP, (l == 0) ? p1 : p2, bP);
            double ev = dexp_fast(lg);
            ((float*)(L12 + m.y))[l] = lg;
            if (l == 0) unsafeAtomicAdd(s1d + m.x, ev);
            else        s2acc += ev;
        }
    }
    if (l == 1) s2d[c] = s2acc;
}

// ---- overflow edges (expected count 0): full per-edge processing.
__global__ void k_ovf(const float* __restrict__ Xu, const float* __restrict__ CD,
                      const int* __restrict__ OV, const unsigned* __restrict__ ovfc,
                      float2* __restrict__ L12, double* __restrict__ s1d,
                      double* __restrict__ s2d) {
    int n = (int)*ovfc; if (n > OCAP) n = OCAP;
    if (n == 0) return;
    const int gid = (blockIdx.x * blockDim.x + threadIdx.x) >> 4;
    const int ng = (gridDim.x * blockDim.x) >> 4;
    const int l = threadIdx.x & 15;
    for (int i = gid; i < n; i += ng) {
        const int* p = OV + (size_t)i * 6;
        int r = p[0], c = p[1], e = p[2];
        const float4* xu = (const float4*)(Xu + (size_t)r * EMB);
        const float4* cd = (const float4*)(CD + (size_t)c * 256);
        float4 x0 = xu[l], x1 = xu[l + 16];
        float4 cv0 = cd[l], cv1 = cd[l + 16];
        float4 dv0 = cd[l + 32], dv1 = cd[l + 48];
        float p1 = x0.x * cv0.x + x0.y * cv0.y + x0.z * cv0.z + x0.w * cv0.w
                 + x1.x * cv1.x + x1.y * cv1.y + x1.z * cv1.z + x1.w * cv1.w;
        float p2 = x0.x * dv0.x + x0.y * dv0.y + x0.z * dv0.z + x0.w * dv0.w
                 + x1.x * dv1.x + x1.y * dv1.y + x1.z * dv1.z + x1.w * dv1.w;
#pragma unroll
        for (int off = 1; off < 16; off <<= 1) {
            p1 += __shfl_xor(p1, off);
            p2 += __shfl_xor(p2, off);
        }
        if (l < 2) {
            float aP = __int_as_float(p[3]);
            float bP = __int_as_float((l == 0) ? p[4] : p[5]);
            float lg = fmaf(aP, (l == 0) ? p1 : p2, bP);
            double ev = dexp_fast(lg);
            ((float*)(L12 + e))[l] = lg;
            if (l == 0) unsafeAtomicAdd(s1d + r, ev);
            else        unsafeAtomicAdd(s2d + c, ev);
        }
    }
}

// ---- final: coalesced; out = dexp(lg)/s in double (s tables L2-hot)
__global__ void k_fin5(const int* __restrict__ rows, const int* __restrict__ cols,
                       const float2* __restrict__ L12,
                       const double* __restrict__ s1d, const double* __restrict__ s2d,
                       float* __restrict__ out, int nnz) {
    int i = blockIdx.x * blockDim.x + threadIdx.x, st = gridDim.x * blockDim.x;
    for (int e = i; e < nnz; e += st) {
        float2 lg = L12[e];
        out[e]       = (float)(dexp_fast(lg.x) / s1d[rows[e]]);
        out[nnz + e] = (float)(dexp_fast(lg.y) / s2d[cols[e]]);
    }
}

// ================= fallback (unsorted, max-based) path =================
__global__ __launch_bounds__(256) void k_cd(const float* __restrict__ Xi,
                                            const float* __restrict__ BIGM,
                                            float* __restrict__ CD, int nItems) {
    __shared__ float Xs[32][EMB];
    __shared__ float Ms[32][256];
    const int t = threadIdx.x;
    const int m0 = blockIdx.x * 32;
    const float4* Xi4 = (const float4*)Xi;
    float4* Xs4 = (float4*)Xs;
    for (int idx = t; idx < 32 * 32; idx += 256) {
        int r = idx >> 5, c = idx & 31;
        int row = m0 + r;
        Xs4[idx] = (row < nItems) ? Xi4[(size_t)row * 32 + c]
                                  : make_float4(0.f, 0.f, 0.f, 0.f);
    }
    const int tc = t & 63;
    const int tr = t >> 6;
    float4 acc[8] = {};
    const float4* BG4 = (const float4*)BIGM;
    float4* Ms4 = (float4*)Ms;
    for (int kc = 0; kc < EMB; kc += 32) {
        __syncthreads();
        for (int idx = t; idx < 32 * 64; idx += 256)
            Ms4[idx] = BG4[(size_t)(kc + (idx >> 6)) * 64 + (idx & 63)];
        __syncthreads();
#pragma unroll
        for (int kk = 0; kk < 32; ++kk) {
            float4 w = Ms4[kk * 64 + tc];
#pragma unroll
            for (int i = 0; i < 8; ++i) {
                float x = Xs[tr * 8 + i][kc + kk];
                acc[i].x += x * w.x; acc[i].y += x * w.y;
                acc[i].z += x * w.z; acc[i].w += x * w.w;
            }
        }
    }
#pragma unroll
    for (int i = 0; i < 8; ++i) {
        int row = m0 + tr * 8 + i;
        if (row < nItems)
            ((float4*)(CD + (size_t)row * 256))[tc] = acc[i];
    }
}

__global__ __launch_bounds__(256) void k_edge1(
    const float* __restrict__ Xu, const float* __restrict__ CD,
    const float2* __restrict__ t12, const float2* __restrict__ u12,
    const float* __restrict__ c0p, const float* __restrict__ adj,
    const float* __restrict__ gu1, const float* __restrict__ gu2,
    const int* __restrict__ rows, const int* __restrict__ cols,
    float* __restrict__ L1, float* __restrict__ L2,
    unsigned* __restrict__ mx1, unsigned* __restrict__ mx2, int nnz) {
    const int gid = blockIdx.x * 8 + (threadIdx.x >> 5);
    const int l = threadIdx.x & 31;
    const int stride = gridDim.x * 8;
    const float c0 = c0p[0];
    const bool useb = (c0p[1] != 0.f);
    for (int e = gid; e < nnz; e += stride) {
        int r = rows[e], c = cols[e];
        float4 xu = ((const float4*)(Xu + (size_t)r * EMB))[l];
        const float4* cd = (const float4*)(CD + (size_t)c * 256);
        float4 cv = cd[l];
        float4 dv = cd[32 + l];
        float p1 = xu.x * cv.x + xu.y * cv.y + xu.z * cv.z + xu.w * cv.w;
        float p2 = xu.x * dv.x + xu.y * dv.y + xu.z * dv.z + xu.w * dv.w;
        for (int off = 16; off; off >>= 1) { p1 += __shfl_xor(p1, off); p2 += __shfl_xor(p2, off); }
        if (l < 2) {
            float p = (l == 0) ? p1 : p2;
            float tb = 0.f, ub = 0.f;
            if (useb) {
                float2 tt = t12[r];
                float2 uu = u12[c];
                tb = (l == 0) ? tt.x : tt.y;
                ub = (l == 0) ? uu.x : uu.y;
            }
            float g = logf(-logf(((l == 0) ? gu1 : gu2)[e]));
            float w = adj[e] * (p + tb + ub + c0);
            float lg = (w - g) * TAUINV;
            if (l == 0) { L1[e] = lg; atomicMax(mx1 + r, fkey(lg)); }
            else        { L2[e] = lg; atomicMax(mx2 + c, fkey(lg)); }
        }
    }
}

__global__ void k_sum(const int* __restrict__ rows, const int* __restrict__ cols,
                      const float* __restrict__ L1, const float* __restrict__ L2,
                      const unsigned* __restrict__ mx1, const unsigned* __restrict__ mx2,
                      float* __restrict__ s1, float* __restrict__ s2, int nnz) {
    int i = blockIdx.x * blockDim.x + threadIdx.x, st = gridDim.x * blockDim.x;
    for (int e = i; e < nnz; e += st) {
        int r = rows[e], c = cols[e];
        atomicAdd(s1 + r, expf(L1[e] - fdecode(mx1[r])));
        atomicAdd(s2 + c, expf(L2[e] - fdecode(mx2[c])));
    }
}

__global__ void k_fin2(const int* __restrict__ rows, const int* __restrict__ cols,
                       const float* __restrict__ L1, const float* __restrict__ L2,
                       const unsigned* __restrict__ mx1, const unsigned* __restrict__ mx2,
                       const float* __restrict__ s1, const float* __restrict__ s2,
                       float* __restrict__ out, int nnz) {
    int i = blockIdx.x * blockDim.x + threadIdx.x, st = gridDim.x * blockDim.x;
    for (int e = i; e < nnz; e += st) {
        int r = rows[e], c = cols[e];
        out[e]       = expf(L1[e] - fdecode(mx1[r])) / s1[r];
        out[nnz + e] = expf(L2[e] - fdecode(mx2[c])) / s2[c];
    }
}

extern "C" void kernel_launch(void* const* d_in, const int* in_sizes, int n_in,
                              void* d_out, int out_size, void* d_ws, size_t ws_size,
                              hipStream_t stream) {
    const float* Xu  = (const float*)d_in[0];
    const float* Xi  = (const float*)d_in[1];
    const float* Wq  = (const float*)d_in[2];
    const float* bq  = (const float*)d_in[3];
    const float* Wk  = (const float*)d_in[4];
    const float* bk  = (const float*)d_in[5];
    const float* adj = (const float*)d_in[6];
    const float* gu1 = (const float*)d_in[7];
    const float* gu2 = (const float*)d_in[8];
    const int* rows  = (const int*)d_in[9];
    const int* cols  = (const int*)d_in[10];
    float* out = (float*)d_out;

    const int U   = in_sizes[0] / EMB;
    const int I   = in_sizes[1] / EMB;
    const int nnz = in_sizes[6];
    const int nbCD = (I + 31) / 32;

    char* w = (char*)d_ws;
    size_t off_b = 0;
    auto alloc = [&](size_t bytes) {
        char* p = w + off_b;
        off_b += (bytes + 15) & ~(size_t)15;
        return p;
    };

    float* BIGM = (float*)alloc(32768 * 4);
    float* v1   = (float*)alloc(128 * 4);
    float* v2   = (float*)alloc(128 * 4);
    float* c0   = (float*)alloc(64 * 4);      // [0]=c0, [1]=bias flag
    float2* t12 = (float2*)alloc((size_t)U * 8);
    float2* u12 = (float2*)alloc((size_t)I * 8);
    float* CD   = (float*)alloc((size_t)I * 256 * 4);
    float2* L12 = (float2*)alloc((size_t)nnz * 8);
    size_t base_need = off_b;
    // sorted-path extras: s1d + cnt + ovfc contiguous -> single memset
    double* s1d    = (double*)alloc((size_t)U * 8);
    unsigned* cnt  = (unsigned*)alloc((size_t)I * 4);
    unsigned* ovfc = (unsigned*)alloc(16 * 4);
    double* s2d    = (double*)alloc((size_t)I * 8);
    int4* SA = (int4*)alloc((size_t)I * CAP * 16);
    int* OV = (int*)alloc((size_t)OCAP * 24);
    size_t sorted_need = off_b;
    // fallback extras
    unsigned* mx1 = (unsigned*)alloc((size_t)U * 4);
    unsigned* mx2 = (unsigned*)alloc((size_t)I * 4);
    float* s1f  = (float*)alloc((size_t)U * 4);
    float* s2f  = (float*)alloc((size_t)I * 4);
    size_t fallback_need = off_b;

    const bool use_sorted = (sorted_need <= ws_size);
    if (!use_sorted && fallback_need > ws_size) return;

    k_prep<<<128, 128, 0, stream>>>(Wq, Wk, bq, bk, BIGM, v1, v2, c0);
    k_rowdot2<<<(U + I + 7) / 8, 256, 0, stream>>>(Xu, Xi, U, I, v1, v2, c0,
                                                   t12, u12);

    if (use_sorted) {
        // zero s1d (U doubles) + cnt (I uints) + ovfc in one memset
        (void)hipMemsetAsync(s1d, 0, (size_t)U * 8 + (size_t)I * 4 + 64, stream);
        k_mid<<<nbCD + NSCAT, 256, 0, stream>>>(Xi, BIGM, CD, I, nbCD,
                                                rows, cols, adj, gu1, gu2,
                                                t12, u12, c0, nnz, cnt, SA,
                                                OV, ovfc);
        k_edge14<<<(I + 15) / 16, 256, 0, stream>>>(Xu, CD, cnt, SA, L12,
                                                    s1d, s2d, I);
        k_ovf<<<64, 256, 0, stream>>>(Xu, CD, OV, ovfc, L12, s1d, s2d);
        k_fin5<<<2048, 256, 0, stream>>>(rows, cols, L12, s1d, s2d, out, nnz);
    } else {
        float* L1 = (float*)L12;
        float* L2 = L1 + nnz;
        (void)hipMemsetAsync(mx1, 0, (size_t)(2 * (U + I)) * 4, stream);
        k_cd<<<nbCD, 256, 0, stream>>>(Xi, BIGM, CD, I);
        k_edge1<<<4096, 256, 0, stream>>>(Xu, CD, t12, u12, c0, adj, gu1, gu2,
                                          rows, cols, L1, L2, mx1, mx2, nnz);
        k_sum<<<2048, 256, 0, stream>>>(rows, cols, L1, L2, mx1, mx2, s1f, s2f, nnz);
        k_fin2<<<2048, 256, 0, stream>>>(rows, cols, L1, L2, mx1, mx2, s1f, s2f,
                                         out, nnz);
    }
}

// Round 20
// 332.118 us; speedup vs baseline: 1.2678x; 1.0100x over previous
//
#include <hip/hip_runtime.h>
#include <hip/hip_bf16.h>
#include <hip/hip_fp16.h>

// Sparse graph-attention Gumbel mask.
//
// With M = Wq^T Wk [E,E]:
//   w_ui[e] = adj*( Xu[r]·C[c] + t1[r] + u1[c] + c0 ),  C = Xi M^T
//   w_iu[e] = adj*( Xu[r]·D[c] + t2[r] + u2[c] + c0 ),  D = Xi M
//
// R20 = R19 (fixed-cap c-binning, fused cd+scatter k_mid, bin-per-16-lane
// edge kernel, half2 b-pack -> one 16B scattered store/edge, no-max f64
// softmax, f64-divide fin) + dispatch consolidation:
//  - workspace zeroing moved into k_prep (memset dispatch killed)
//  - overflow handling folded into k_edge14 trailing blocks (k_ovf killed);
//    s2d now via unsafeAtomicAdd (pre-zeroed) so ordering is free
//  - rowdot2 grid-stride with small grid (bias-zero early-exit ~2us)

#define EMB 128
#define TAUINV 2.0f
#define LOG2E 1.44269504f
#define CAP 128
#define OCAP 65536
#define NSCAT 2048

__device__ __forceinline__ unsigned fkey(float f) {
    unsigned u = __float_as_uint(f);
    return (u & 0x80000000u) ? ~u : (u | 0x80000000u);
}
__device__ __forceinline__ float fdecode(unsigned u) {
    return __uint_as_float((u & 0x80000000u) ? (u ^ 0x80000000u) : ~u);
}

// exp(lg) as double without overflow: exp2f fraction + ldexp integer part.
__device__ __forceinline__ double dexp_fast(float lg) {
    float t = lg * LOG2E;
    float kf = floorf(t);
    float f = exp2f(t - kf);
    return ldexp((double)f, (int)kf);
}

// ---- BIGM[k][j] (j<128: M[j][k]; j>=128: M[k][j-128]), v1, v2, c0, flag
//      + zeroes the accumulator region (s1d/cnt/ovfc/s2d)
__global__ void k_prep(const float* __restrict__ Wq, const float* __restrict__ Wk,
                       const float* __restrict__ bq, const float* __restrict__ bk,
                       float* __restrict__ BIGM, float* __restrict__ v1,
                       float* __restrict__ v2, float* __restrict__ c0,
                       float4* __restrict__ zbase, int zquads) {
    int e1 = blockIdx.x, e2 = threadIdx.x;
    // zero accumulators (16384 threads stride over 16B quads)
    for (int i = e1 * 128 + e2; i < zquads; i += 128 * 128)
        zbase[i] = make_float4(0.f, 0.f, 0.f, 0.f);
    float acc = 0.f;
    for (int a = 0; a < EMB; ++a) acc += Wq[a * EMB + e1] * Wk[a * EMB + e2];
    BIGM[e2 * 256 + e1] = acc;
    BIGM[e1 * 256 + 128 + e2] = acc;
    if (e2 == 0) { float s = 0.f; for (int a = 0; a < EMB; ++a) s += Wq[a * EMB + e1] * bk[a]; v1[e1] = s; }
    if (e2 == 1) { float s = 0.f; for (int a = 0; a < EMB; ++a) s += Wk[a * EMB + e1] * bq[a]; v2[e1] = s; }
    if (e1 == 0 && e2 == 2) { float s = 0.f; for (int a = 0; a < EMB; ++a) s += bq[a] * bk[a]; c0[0] = s; }
    if (e1 == 0 && e2 == 3) { float s = 0.f; for (int a = 0; a < EMB; ++a) s += fabsf(bq[a]) + fabsf(bk[a]); c0[1] = s; }
}

// ---- fused rowdots (grid-stride; near-free early exit when biases zero)
__global__ void k_rowdot2(const float* __restrict__ Xu, const float* __restrict__ Xi,
                          int U, int I,
                          const float* __restrict__ v1, const float* __restrict__ v2,
                          const float* __restrict__ c0p,
                          float2* __restrict__ t12, float2* __restrict__ u12) {
    if (c0p[1] == 0.f) return;   // all biases zero -> t12/u12 never read
    int l = threadIdx.x & 31;
    int g0 = blockIdx.x * 8 + (threadIdx.x >> 5);
    int gst = gridDim.x * 8;
    for (int g = g0; g < U + I; g += gst) {
        const float* X = (g < U) ? (Xu + (size_t)g * EMB) : (Xi + (size_t)(g - U) * EMB);
        float4 x = ((const float4*)X)[l];
        float4 av = ((const float4*)v1)[l];
        float4 bv = ((const float4*)v2)[l];
        float pa = x.x * av.x + x.y * av.y + x.z * av.z + x.w * av.w;
        float pb = x.x * bv.x + x.y * bv.y + x.z * bv.z + x.w * bv.w;
        for (int off = 16; off; off >>= 1) { pa += __shfl_xor(pa, off); pb += __shfl_xor(pb, off); }
        if (l == 0) {
            if (g < U) t12[g] = make_float2(pa, pb);
            else       u12[g - U] = make_float2(pb, pa);
        }
    }
}

// ---- FUSED: blocks [0,nbCD) = CD GEMM; blocks [nbCD, nbCD+NSCAT) = scatter
__global__ __launch_bounds__(256) void k_mid(
    const float* __restrict__ Xi, const float* __restrict__ BIGM,
    float* __restrict__ CD, int nItems, int nbCD,
    const int* __restrict__ rows, const int* __restrict__ cols,
    const float* __restrict__ adj, const float* __restrict__ gu1,
    const float* __restrict__ gu2,
    const float2* __restrict__ t12, const float2* __restrict__ u12,
    const float* __restrict__ c0p, int nnz,
    unsigned* __restrict__ cnt, int4* __restrict__ SA,
    int* __restrict__ OV, unsigned* __restrict__ ovfc) {
    __shared__ float Xs[32][EMB];
    __shared__ float Ms[32][256];
    if (blockIdx.x < (unsigned)nbCD) {
        // ======== CD GEMM body ========
        const int t = threadIdx.x;
        const int m0 = blockIdx.x * 32;

        const float4* Xi4 = (const float4*)Xi;
        float4* Xs4 = (float4*)Xs;
        for (int idx = t; idx < 32 * 32; idx += 256) {
            int r = idx >> 5, c = idx & 31;
            int row = m0 + r;
            Xs4[idx] = (row < nItems) ? Xi4[(size_t)row * 32 + c]
                                      : make_float4(0.f, 0.f, 0.f, 0.f);
        }

        const int tc = t & 63;
        const int tr = t >> 6;
        float4 acc[8] = {};

        const float4* BG4 = (const float4*)BIGM;
        float4* Ms4 = (float4*)Ms;
        for (int kc = 0; kc < EMB; kc += 32) {
            __syncthreads();
            for (int idx = t; idx < 32 * 64; idx += 256)
                Ms4[idx] = BG4[(size_t)(kc + (idx >> 6)) * 64 + (idx & 63)];
            __syncthreads();
#pragma unroll
            for (int kk = 0; kk < 32; ++kk) {
                float4 w = Ms4[kk * 64 + tc];
#pragma unroll
                for (int i = 0; i < 8; ++i) {
                    float x = Xs[tr * 8 + i][kc + kk];
                    acc[i].x += x * w.x; acc[i].y += x * w.y;
                    acc[i].z += x * w.z; acc[i].w += x * w.w;
                }
            }
        }
#pragma unroll
        for (int i = 0; i < 8; ++i) {
            int row = m0 + tr * 8 + i;
            if (row < nItems)
                ((float4*)(CD + (size_t)row * 256))[tc] = acc[i];
        }
    } else {
        // ======== scatter body: ONE 16B store per edge ========
        const float c0 = c0p[0];
        const bool useb = (c0p[1] != 0.f);
        int i = (blockIdx.x - nbCD) * blockDim.x + threadIdx.x;
        int st = NSCAT * blockDim.x;
        for (int e = i; e < nnz; e += st) {
            int r = rows[e], c = cols[e];
            unsigned pos = atomicAdd(&cnt[c], 1u);
            float a = adj[e];
            float g1 = logf(-logf(gu1[e]));   // logf: u near 1 needs rel accuracy
            float g2 = logf(-logf(gu2[e]));
            float b1 = -g1 * TAUINV;
            float b2 = -g2 * TAUINV;
            if (useb) {
                float2 tt = t12[r];
                float2 uu = u12[c];
                b1 += a * (tt.x + uu.x + c0) * TAUINV;
                b2 += a * (tt.y + uu.y + c0) * TAUINV;
            }
            if (pos < CAP) {
                __half2 hb = __floats2half2_rn(b1, b2);
                SA[(size_t)c * CAP + pos] =
                    make_int4(r, e, __float_as_int(a * TAUINV),
                              *(const int*)&hb);
            } else {
                unsigned o = atomicAdd(ovfc, 1u);
                if (o < OCAP) {
                    int* p = OV + (size_t)o * 6;
                    p[0] = r; p[1] = c; p[2] = e;
                    p[3] = __float_as_int(a * TAUINV);
                    p[4] = __float_as_int(b1); p[5] = __float_as_int(b2);
                }
            }
        }
    }
}

// ---- edge kernel: blocks [0,nbE) = bins (one bin per 16-lane group, CD
// register-held, lane0/1 tail split, fast exp); blocks [nbE, nbE+64) =
// overflow edges (expected none). s2d via atomics (pre-zeroed) -> no
// ordering requirement between the two block families.
__global__ __launch_bounds__(256) void k_edge14(
    const float* __restrict__ Xu, const float* __restrict__ CD,
    const unsigned* __restrict__ cnt, const int4* __restrict__ SA,
    const int* __restrict__ OV, const unsigned* __restrict__ ovfc,
    float2* __restrict__ L12, double* __restrict__ s1d, double* __restrict__ s2d,
    int I, int nbE) {
    if (blockIdx.x < (unsigned)nbE) {
        const int g = threadIdx.x >> 4, l = threadIdx.x & 15;
        const int c = blockIdx.x * 16 + g;
        if (c >= I) return;
        unsigned n = cnt[c]; if (n > CAP) n = CAP;
        if (n == 0) return;
        const unsigned lo = (unsigned)c * CAP;
        const unsigned hi = lo + n;
        const float4* cd = (const float4*)(CD + (size_t)c * 256);
        const float4 cv0 = cd[l], cv1 = cd[l + 16];
        const float4 dv0 = cd[l + 32], dv1 = cd[l + 48];
        double s2acc = 0.0;
        for (unsigned j = lo; j < hi; ++j) {
            int4 m = SA[j];
            const float4* xu = (const float4*)(Xu + (size_t)m.x * EMB);
            float4 x0 = xu[l], x1 = xu[l + 16];
            float p1 = x0.x * cv0.x + x0.y * cv0.y + x0.z * cv0.z + x0.w * cv0.w
                     + x1.x * cv1.x + x1.y * cv1.y + x1.z * cv1.z + x1.w * cv1.w;
            float p2 = x0.x * dv0.x + x0.y * dv0.y + x0.z * dv0.z + x0.w * dv0.w
                     + x1.x * dv1.x + x1.y * dv1.y + x1.z * dv1.z + x1.w * dv1.w;
#pragma unroll
            for (int off = 1; off < 16; off <<= 1) {
                p1 += __shfl_xor(p1, off);
                p2 += __shfl_xor(p2, off);
            }
            if (l < 2) {
                __half2 hb = *(const __half2*)&m.w;
                float aP = __int_as_float(m.z);
                float bP = (l == 0) ? __low2float(hb) : __high2float(hb);
                float lg = fmaf(aP, (l == 0) ? p1 : p2, bP);
                double ev = dexp_fast(lg);
                ((float*)(L12 + m.y))[l] = lg;
                if (l == 0) unsafeAtomicAdd(s1d + m.x, ev);
                else        s2acc += ev;
            }
        }
        if (l == 1) unsafeAtomicAdd(s2d + c, s2acc);
    } else {
        // ---- overflow edges (expected count 0)
        int n = (int)*ovfc; if (n > OCAP) n = OCAP;
        if (n == 0) return;
        const int gid = ((blockIdx.x - nbE) * blockDim.x + threadIdx.x) >> 4;
        const int ng = (64 * 256) >> 4;
        const int l = threadIdx.x & 15;
        for (int i = gid; i < n; i += ng) {
            const int* p = OV + (size_t)i * 6;
            int r = p[0], c = p[1], e = p[2];
            const float4* xu = (const float4*)(Xu + (size_t)r * EMB);
            const float4* cd = (const float4*)(CD + (size_t)c * 256);
            float4 x0 = xu[l], x1 = xu[l + 16];
            float4 cv0 = cd[l], cv1 = cd[l + 16];
            float4 dv0 = cd[l + 32], dv1 = cd[l + 48];
            float p1 = x0.x * cv0.x + x0.y * cv0.y + x0.z * cv0.z + x0.w * cv0.w
                     + x1.x * cv1.x + x1.y * cv1.y + x1.z * cv1.z + x1.w * cv1.w;
            float p2 = x0.x * dv0.x + x0.y * dv0.y + x0.z * dv0.z + x0.w * dv0.w
                     + x1.x * dv1.x + x1.y * dv1.y + x1.z * dv1.z + x1.w * dv1.w;
#pragma unroll
            for (int off = 1; off < 16; off <<= 1) {
                p1 += __shfl_xor(p1, off);
                p2 += __shfl_xor(p2, off);
            }
            if (l < 2) {
                float aP = __int_as_float(p[3]);
                float bP = __int_as_float((l == 0) ? p[4] : p[5]);
                float lg = fmaf(aP, (l == 0) ? p1 : p2, bP);
                double ev = dexp_fast(lg);
                ((float*)(L12 + e))[l] = lg;
                if (l == 0) unsafeAtomicAdd(s1d + r, ev);
                else        unsafeAtomicAdd(s2d + c, ev);
            }
        }
    }
}

// ---- final: coalesced; out = dexp(lg)/s in double (s tables L2-hot)
__global__ void k_fin5(const int* __restrict__ rows, const int* __restrict__ cols,
                       const float2* __restrict__ L12,
                       const double* __restrict__ s1d, const double* __restrict__ s2d,
                       float* __restrict__ out, int nnz) {
    int i = blockIdx.x * blockDim.x + threadIdx.x, st = gridDim.x * blockDim.x;
    for (int e = i; e < nnz; e += st) {
        float2 lg = L12[e];
        out[e]       = (float)(dexp_fast(lg.x) / s1d[rows[e]]);
        out[nnz + e] = (float)(dexp_fast(lg.y) / s2d[cols[e]]);
    }
}

// ================= fallback (unsorted, max-based) path =================
__global__ __launch_bounds__(256) void k_cd(const float* __restrict__ Xi,
                                            const float* __restrict__ BIGM,
                                            float* __restrict__ CD, int nItems) {
    __shared__ float Xs[32][EMB];
    __shared__ float Ms[32][256];
    const int t = threadIdx.x;
    const int m0 = blockIdx.x * 32;
    const float4* Xi4 = (const float4*)Xi;
    float4* Xs4 = (float4*)Xs;
    for (int idx = t; idx < 32 * 32; idx += 256) {
        int r = idx >> 5, c = idx & 31;
        int row = m0 + r;
        Xs4[idx] = (row < nItems) ? Xi4[(size_t)row * 32 + c]
                                  : make_float4(0.f, 0.f, 0.f, 0.f);
    }
    const int tc = t & 63;
    const int tr = t >> 6;
    float4 acc[8] = {};
    const float4* BG4 = (const float4*)BIGM;
    float4* Ms4 = (float4*)Ms;
    for (int kc = 0; kc < EMB; kc += 32) {
        __syncthreads();
        for (int idx = t; idx < 32 * 64; idx += 256)
            Ms4[idx] = BG4[(size_t)(kc + (idx >> 6)) * 64 + (idx & 63)];
        __syncthreads();
#pragma unroll
        for (int kk = 0; kk < 32; ++kk) {
            float4 w = Ms4[kk * 64 + tc];
#pragma unroll
            for (int i = 0; i < 8; ++i) {
                float x = Xs[tr * 8 + i][kc + kk];
                acc[i].x += x * w.x; acc[i].y += x * w.y;
                acc[i].z += x * w.z; acc[i].w += x * w.w;
            }
        }
    }
#pragma unroll
    for (int i = 0; i < 8; ++i) {
        int row = m0 + tr * 8 + i;
        if (row < nItems)
            ((float4*)(CD + (size_t)row * 256))[tc] = acc[i];
    }
}

__global__ __launch_bounds__(256) void k_edge1(
    const float* __restrict__ Xu, const float* __restrict__ CD,
    const float2* __restrict__ t12, const float2* __restrict__ u12,
    const float* __restrict__ c0p, const float* __restrict__ adj,
    const float* __restrict__ gu1, const float* __restrict__ gu2,
    const int* __restrict__ rows, const int* __restrict__ cols,
    float* __restrict__ L1, float* __restrict__ L2,
    unsigned* __restrict__ mx1, unsigned* __restrict__ mx2, int nnz) {
    const int gid = blockIdx.x * 8 + (threadIdx.x >> 5);
    const int l = threadIdx.x & 31;
    const int stride = gridDim.x * 8;
    const float c0 = c0p[0];
    const bool useb = (c0p[1] != 0.f);
    for (int e = gid; e < nnz; e += stride) {
        int r = rows[e], c = cols[e];
        float4 xu = ((const float4*)(Xu + (size_t)r * EMB))[l];
        const float4* cd = (const float4*)(CD + (size_t)c * 256);
        float4 cv = cd[l];
        float4 dv = cd[32 + l];
        float p1 = xu.x * cv.x + xu.y * cv.y + xu.z * cv.z + xu.w * cv.w;
        float p2 = xu.x * dv.x + xu.y * dv.y + xu.z * dv.z + xu.w * dv.w;
        for (int off = 16; off; off >>= 1) { p1 += __shfl_xor(p1, off); p2 += __shfl_xor(p2, off); }
        if (l < 2) {
            float p = (l == 0) ? p1 : p2;
            float tb = 0.f, ub = 0.f;
            if (useb) {
                float2 tt = t12[r];
                float2 uu = u12[c];
                tb = (l == 0) ? tt.x : tt.y;
                ub = (l == 0) ? uu.x : uu.y;
            }
            float g = logf(-logf(((l == 0) ? gu1 : gu2)[e]));
            float w = adj[e] * (p + tb + ub + c0);
            float lg = (w - g) * TAUINV;
            if (l == 0) { L1[e] = lg; atomicMax(mx1 + r, fkey(lg)); }
            else        { L2[e] = lg; atomicMax(mx2 + c, fkey(lg)); }
        }
    }
}

__global__ void k_sum(const int* __restrict__ rows, const int* __restrict__ cols,
                      const float* __restrict__ L1, const float* __restrict__ L2,
                      const unsigned* __restrict__ mx1, const unsigned* __restrict__ mx2,
                      float* __restrict__ s1, float* __restrict__ s2, int nnz) {
    int i = blockIdx.x * blockDim.x + threadIdx.x, st = gridDim.x * blockDim.x;
    for (int e = i; e < nnz; e += st) {
        int r = rows[e], c = cols[e];
        atomicAdd(s1 + r, expf(L1[e] - fdecode(mx1[r])));
        atomicAdd(s2 + c, expf(L2[e] - fdecode(mx2[c])));
    }
}

__global__ void k_fin2(const int* __restrict__ rows, const int* __restrict__ cols,
                       const float* __restrict__ L1, const float* __restrict__ L2,
                       const unsigned* __restrict__ mx1, const unsigned* __restrict__ mx2,
                       const float* __restrict__ s1, const float* __restrict__ s2,
                       float* __restrict__ out, int nnz) {
    int i = blockIdx.x * blockDim.x + threadIdx.x, st = gridDim.x * blockDim.x;
    for (int e = i; e < nnz; e += st) {
        int r = rows[e], c = cols[e];
        out[e]       = expf(L1[e] - fdecode(mx1[r])) / s1[r];
        out[nnz + e] = expf(L2[e] - fdecode(mx2[c])) / s2[c];
    }
}

extern "C" void kernel_launch(void* const* d_in, const int* in_sizes, int n_in,
                              void* d_out, int out_size, void* d_ws, size_t ws_size,
                              hipStream_t stream) {
    const float* Xu  = (const float*)d_in[0];
    const float* Xi  = (const float*)d_in[1];
    const float* Wq  = (const float*)d_in[2];
    const float* bq  = (const float*)d_in[3];
    const float* Wk  = (const float*)d_in[4];
    const float* bk  = (const float*)d_in[5];
    const float* adj = (const float*)d_in[6];
    const float* gu1 = (const float*)d_in[7];
    const float* gu2 = (const float*)d_in[8];
    const int* rows  = (const int*)d_in[9];
    const int* cols  = (const int*)d_in[10];
    float* out = (float*)d_out;

    const int U   = in_sizes[0] / EMB;
    const int I   = in_sizes[1] / EMB;
    const int nnz = in_sizes[6];
    const int nbCD = (I + 31) / 32;
    const int nbE  = (I + 15) / 16;

    char* w = (char*)d_ws;
    size_t off_b = 0;
    auto alloc = [&](size_t bytes) {
        char* p = w + off_b;
        off_b += (bytes + 15) & ~(size_t)15;
        return p;
    };

    float* BIGM = (float*)alloc(32768 * 4);
    float* v1   = (float*)alloc(128 * 4);
    float* v2   = (float*)alloc(128 * 4);
    float* c0   = (float*)alloc(64 * 4);      // [0]=c0, [1]=bias flag
    float2* t12 = (float2*)alloc((size_t)U * 8);
    float2* u12 = (float2*)alloc((size_t)I * 8);
    float* CD   = (float*)alloc((size_t)I * 256 * 4);
    float2* L12 = (float2*)alloc((size_t)nnz * 8);
    size_t base_need = off_b;
    // sorted-path accumulators (contiguous, zeroed by k_prep):
    // s1d, cnt, ovfc, s2d
    char* zbase = w + off_b;
    double* s1d    = (double*)alloc((size_t)U * 8);
    unsigned* cnt  = (unsigned*)alloc((size_t)I * 4);
    unsigned* ovfc = (unsigned*)alloc(16 * 4);
    double* s2d    = (double*)alloc((size_t)I * 8);
    size_t zbytes = (size_t)((w + off_b) - zbase);
    int4* SA = (int4*)alloc((size_t)I * CAP * 16);
    int* OV = (int*)alloc((size_t)OCAP * 24);
    size_t sorted_need = off_b;
    // fallback extras
    unsigned* mx1 = (unsigned*)alloc((size_t)U * 4);
    unsigned* mx2 = (unsigned*)alloc((size_t)I * 4);
    float* s1f  = (float*)alloc((size_t)U * 4);
    float* s2f  = (float*)alloc((size_t)I * 4);
    size_t fallback_need = off_b;

    const bool use_sorted = (sorted_need <= ws_size);
    if (!use_sorted && fallback_need > ws_size) return;

    const int zquads = use_sorted ? (int)(zbytes / 16) : 0;
    k_prep<<<128, 128, 0, stream>>>(Wq, Wk, bq, bk, BIGM, v1, v2, c0,
                                    (float4*)zbase, zquads);
    k_rowdot2<<<1280, 256, 0, stream>>>(Xu, Xi, U, I, v1, v2, c0, t12, u12);

    if (use_sorted) {
        k_mid<<<nbCD + NSCAT, 256, 0, stream>>>(Xi, BIGM, CD, I, nbCD,
                                                rows, cols, adj, gu1, gu2,
                                                t12, u12, c0, nnz, cnt, SA,
                                                OV, ovfc);
        k_edge14<<<nbE + 64, 256, 0, stream>>>(Xu, CD, cnt, SA, OV, ovfc, L12,
                                               s1d, s2d, I, nbE);
        k_fin5<<<2048, 256, 0, stream>>>(rows, cols, L12, s1d, s2d, out, nnz);
    } else {
        float* L1 = (float*)L12;
        float* L2 = L1 + nnz;
        (void)hipMemsetAsync(mx1, 0, (size_t)(2 * (U + I)) * 4, stream);
        k_cd<<<nbCD, 256, 0, stream>>>(Xi, BIGM, CD, I);
        k_edge1<<<4096, 256, 0, stream>>>(Xu, CD, t12, u12, c0, adj, gu1, gu2,
                                          rows, cols, L1, L2, mx1, mx2, nnz);
        k_sum<<<2048, 256, 0, stream>>>(rows, cols, L1, L2, mx1, mx2, s1f, s2f, nnz);
        k_fin2<<<2048, 256, 0, stream>>>(rows, cols, L1, L2, mx1, mx2, s1f, s2f,
                                         out, nnz);
    }
}